// Round 3
// baseline (713.401 us; speedup 1.0000x reference)
//
#include <hip/hip_runtime.h>

// Problem constants (from reference): N=4096 agents, TOP_K=12, OBS_RADIUS=1.0
#define NN    4096
#define TOPK  12
#define NP    (NN * TOPK)        // 49152 pairs
// d_out layout (float32): out[0..NP), mask[NP..2NP), indices[2NP..2NP+2NP) as (row, j)
#define OFF_MASK (NP)
#define OFF_IDX  (2 * NP)

// Ascending 64-lane bitonic sort on packed u64 keys (verified in prior kernels).
__device__ __forceinline__ unsigned long long bitonic64(unsigned long long key, int lane) {
    #pragma unroll
    for (int k = 2; k <= 64; k <<= 1) {
        #pragma unroll
        for (int jj = k >> 1; jj >= 1; jj >>= 1) {
            unsigned long long ok = __shfl_xor(key, jj, 64);
            bool keepMin = ((lane & k) == 0) == ((lane & jj) == 0);
            unsigned long long mn = (ok < key) ? ok : key;
            unsigned long long mx = (ok < key) ? key : ok;
            key = keepMin ? mn : mx;
        }
    }
    return key;
}

// ---------------------------------------------------------------------------
// Fused kernel: per-row top-12 (threshold-select, verified structure)
// + per-pair MLP 6->64->128->64->1, one block (256 thr) per row.
//
// Round-7 hardening of the round-6 fusion:
//  - __align__(16) on LDS activation buffers (ds_read_b128 requires 16B
//    alignment; a bare __shared__ float[] base is only 4B-guaranteed —
//    likely cause of the round-6 container fault).
//  - explicit __syncthreads() between MLP phases instead of relying on
//    wave-synchronous LDS ordering (wave 3 idles through; cost is noise).
// Top-k semantics byte-identical to the verified kernel (same keys, same
// sorts, same fallback). MLP: 12 pairs x 16 lanes (threads 0..191).
// ---------------------------------------------------------------------------
__global__ __launch_bounds__(256, 6) void cbf_fused(
        const float* __restrict__ x, const float* __restrict__ rp,
        const float* __restrict__ W1, const float* __restrict__ b1,
        const float* __restrict__ W2, const float* __restrict__ b2,
        const float* __restrict__ W3, const float* __restrict__ b3,
        const float* __restrict__ W4, const float* __restrict__ b4,
        float* __restrict__ out) {
    const int i    = blockIdx.x;   // row
    const int t    = threadIdx.x;  // 0..255
    const int lane = t & 63;
    const int w    = t >> 6;       // wave 0..3
    const float4* x4 = (const float4*)x + (size_t)i * NN;

    // ---------------- top-k phase (unchanged semantics) ----------------
    float s[16];
    #pragma unroll
    for (int k = 0; k < 16; ++k) {
        float4 v = x4[(k << 8) + t];
        s[k] = v.x * v.x + v.y * v.y;
    }

    // Per-thread min as packed key (ascending j scan, strict < => lowest j on tie)
    float bs = s[0]; int bj = t;
    #pragma unroll
    for (int k = 1; k < 16; ++k) {
        int j = (k << 8) + t;
        if (s[k] < bs) { bs = s[k]; bj = j; }
    }
    unsigned long long bk =
        ((unsigned long long)__float_as_uint(bs) << 32) | (unsigned)bj;

    __shared__ unsigned long long cand[64];        // survivor keys (cap 64)
    __shared__ unsigned long long wtop[4 * TOPK];  // per-wave top-12 minima
    __shared__ unsigned long long top12[TOPK];     // final sorted keys
    __shared__ float Tsh;                          // threshold
    __shared__ int   cnt[4];                       // per-wave survivor counts
    // MLP scratch: 16B-aligned bases + 16B-multiple row strides (b128-safe).
    __shared__ __align__(16) float h1sh[TOPK][68];   // 272 B rows
    __shared__ __align__(16) float h2sh[TOPK][132];  // 528 B rows
    __shared__ __align__(16) float p4sh[TOPK][16];

    // Phase A: each wave sorts its 64 lane-minima once; keep its top-12.
    {
        unsigned long long key = bitonic64(bk, lane);
        if (lane < TOPK) wtop[w * TOPK + lane] = key;
    }
    __syncthreads();

    // Phase B: wave 0 sorts the 48 candidates -> exact 12th-smallest minimum T.
    if (w == 0) {
        unsigned long long k2 = (lane < 4 * TOPK) ? wtop[lane] : ~0ULL;
        k2 = bitonic64(k2, lane);
        if (lane == TOPK - 1) Tsh = __uint_as_float((unsigned)(k2 >> 32));
    }
    __syncthreads();
    const float T = Tsh;

    // Phase C: filter register-resident values against T, count + prefix.
    int c = 0;
    #pragma unroll
    for (int k = 0; k < 16; ++k) c += (s[k] <= T) ? 1 : 0;

    int pfx = c;                                   // inclusive scan over wave
    #pragma unroll
    for (int off = 1; off < 64; off <<= 1) {
        int o = __shfl_up(pfx, off, 64);
        if (lane >= off) pfx += o;
    }
    if (lane == 63) cnt[w] = pfx;
    __syncthreads();

    const int total = cnt[0] + cnt[1] + cnt[2] + cnt[3];   // block-uniform

    if (total <= 64) {
        int base = 0;
        for (int ww = 0; ww < w; ++ww) base += cnt[ww];
        int o = base + (pfx - c);                  // exclusive offset
        #pragma unroll
        for (int k = 0; k < 16; ++k) {
            if (s[k] <= T)
                cand[o++] = ((unsigned long long)__float_as_uint(s[k]) << 32)
                            | (unsigned)((k << 8) + t);
        }
        __syncthreads();

        if (w == 0) {
            unsigned long long k3 = (lane < total) ? cand[lane] : ~0ULL;
            k3 = bitonic64(k3, lane);              // total >= 12 guaranteed
            if (lane < TOPK) {
                top12[lane] = k3;
                int   j  = (int)(k3 & 0xffffffffULL);
                float ss = __uint_as_float((unsigned)(k3 >> 32));
                float d  = sqrtf(ss + 2.0e-4f);    // sqrt(sum(x[:2]^2 + 1e-4))
                float m  = (d <= 1.0f) ? 1.0f : 0.0f;
                int p = i * TOPK + lane;
                out[OFF_MASK + p]        = m;
                out[OFF_IDX + 2 * p]     = (float)i;
                out[OFF_IDX + 2 * p + 1] = (float)j;
            }
        }
    } else {
        // -------------------------------------------------------------------
        // Fallback (pathological ties only): original wave-local 12-pop.
        // s[] and bk are untouched by the filter phase.
        // -------------------------------------------------------------------
        unsigned long long mykey = ~0ULL;
        for (int it = 0; it < TOPK; ++it) {
            unsigned long long vk = bk;
            #pragma unroll
            for (int off = 1; off < 64; off <<= 1) {
                unsigned long long ok = __shfl_xor(vk, off, 64);
                vk = (ok < vk) ? ok : vk;
            }
            if (lane == it) mykey = vk;            // record pop #it
            int wj = (int)(vk & 0xffffffffULL);    // winning j (this wave's range)
            if ((wj & 63) == lane) {               // I own it: pop + recompute
                int kk = wj >> 8;
                #pragma unroll
                for (int k = 0; k < 16; ++k)
                    if (k == kk) s[k] = 3.0e38f;
                float nbs = s[0]; int nbj = t;
                #pragma unroll
                for (int k = 1; k < 16; ++k) {
                    int j = (k << 8) + t;
                    if (s[k] < nbs) { nbs = s[k]; nbj = j; }
                }
                bk = ((unsigned long long)__float_as_uint(nbs) << 32) | (unsigned)nbj;
            }
        }
        if (lane < TOPK) cand[w * TOPK + lane] = mykey;
        __syncthreads();

        if (w == 0) {
            unsigned long long k3 = (lane < 4 * TOPK) ? cand[lane] : ~0ULL;
            k3 = bitonic64(k3, lane);
            if (lane < TOPK) {
                top12[lane] = k3;
                int   j  = (int)(k3 & 0xffffffffULL);
                float ss = __uint_as_float((unsigned)(k3 >> 32));
                float d  = sqrtf(ss + 2.0e-4f);
                float m  = (d <= 1.0f) ? 1.0f : 0.0f;
                int p = i * TOPK + lane;
                out[OFF_MASK + p]        = m;
                out[OFF_IDX + 2 * p]     = (float)i;
                out[OFF_IDX + 2 * p + 1] = (float)j;
            }
        }
    }
    __syncthreads();   // top12[] visible to all

    // ---------------- MLP tail: 12 pairs x 16 lanes (threads 0..191) -------
    const bool act = (t < 192);
    const int p = t >> 4;                 // pair slot 0..11 (only if act)
    const int l = t & 15;                 // lane within pair group

    float xin[6];
    float m = 0.0f;
    if (act) {
        const unsigned long long key = top12[p];
        const int   j  = (int)(key & 0xffffffffULL);
        const float ss = __uint_as_float((unsigned)(key >> 32));
        const float d  = sqrtf(ss + 2.0e-4f);
        m = (d <= 1.0f) ? 1.0f : 0.0f;

        const float4 v = x4[j];           // gathered; row is L1/L2-resident
        xin[0] = v.x; xin[1] = v.y; xin[2] = v.z; xin[3] = v.w;
        xin[4] = (i == j) ? 1.0f : 0.0f;
        xin[5] = d - rp[0];

        // Layer 1: lane computes neurons q = l*4+n  (6 MACs each)
        #pragma unroll
        for (int n = 0; n < 4; ++n) {
            int q = l * 4 + n;
            float a = b1[q];
            #pragma unroll
            for (int cc = 0; cc < 6; ++cc) a += W1[q * 6 + cc] * xin[cc];
            h1sh[p][q] = fmaxf(a, 0.0f);
        }
    }
    __syncthreads();

    if (act) {
        // Layer 2: lane computes neurons q2 = l*8+n, k streamed as float4
        float acc2[8];
        #pragma unroll
        for (int n = 0; n < 8; ++n) acc2[n] = b2[l * 8 + n];
        const float4* h1f4 = (const float4*)&h1sh[p][0];
        const float4* w2f4 = (const float4*)W2;
        #pragma unroll
        for (int kk = 0; kk < 16; ++kk) {
            float4 hv = h1f4[kk];
            #pragma unroll
            for (int n = 0; n < 8; ++n) {
                float4 wv = w2f4[(l * 8 + n) * 16 + kk];
                acc2[n] += wv.x * hv.x + wv.y * hv.y + wv.z * hv.z + wv.w * hv.w;
            }
        }
        #pragma unroll
        for (int n = 0; n < 8; ++n) h2sh[p][l * 8 + n] = fmaxf(acc2[n], 0.0f);
    }
    __syncthreads();

    if (act) {
        // Layer 3: lane computes neurons q3 = l*4+n
        float acc3[4];
        #pragma unroll
        for (int n = 0; n < 4; ++n) acc3[n] = b3[l * 4 + n];
        const float4* h2f4 = (const float4*)&h2sh[p][0];
        const float4* w3f4 = (const float4*)W3;
        #pragma unroll
        for (int kk = 0; kk < 32; ++kk) {
            float4 hv = h2f4[kk];
            #pragma unroll
            for (int n = 0; n < 4; ++n) {
                float4 wv = w3f4[(l * 4 + n) * 32 + kk];
                acc3[n] += wv.x * hv.x + wv.y * hv.y + wv.z * hv.z + wv.w * hv.w;
            }
        }
        // Layer 4 partial over my 4 relu'd h3 outputs
        float partial = 0.0f;
        #pragma unroll
        for (int n = 0; n < 4; ++n) partial += W4[l * 4 + n] * fmaxf(acc3[n], 0.0f);
        p4sh[p][l] = partial;
    }
    __syncthreads();

    // Reduce 16 partials (ascending-lane = ascending-neuron order).
    if (act && l == 0) {
        float sum = b4[0];
        #pragma unroll
        for (int cc = 0; cc < 16; ++cc) sum += p4sh[p][cc];
        out[i * TOPK + p] = sum * m;
    }
}

// ---------------------------------------------------------------------------
extern "C" void kernel_launch(void* const* d_in, const int* in_sizes, int n_in,
                              void* d_out, int out_size, void* d_ws, size_t ws_size,
                              hipStream_t stream) {
    const float* x  = (const float*)d_in[0];
    const float* rp = (const float*)d_in[1];
    const float* W1 = (const float*)d_in[2];
    const float* b1 = (const float*)d_in[3];
    const float* W2 = (const float*)d_in[4];
    const float* b2 = (const float*)d_in[5];
    const float* W3 = (const float*)d_in[6];
    const float* b3 = (const float*)d_in[7];
    const float* W4 = (const float*)d_in[8];
    const float* b4 = (const float*)d_in[9];
    float* out = (float*)d_out;

    cbf_fused<<<NN, 256, 0, stream>>>(x, rp, W1, b1, W2, b2, W3, b3, W4, b4, out);
}

// Round 4
// 404.555 us; speedup vs baseline: 1.7634x; 1.7634x over previous
//
#include <hip/hip_runtime.h>

// Problem constants (from reference): N=4096 agents, TOP_K=12, OBS_RADIUS=1.0
#define NN    4096
#define TOPK  12
#define NP    (NN * TOPK)        // 49152 pairs
// d_out layout (float32): out[0..NP), mask[NP..2NP), indices[2NP..2NP+2NP) as (row, j)
#define OFF_MASK (NP)
#define OFF_IDX  (2 * NP)

// Ascending 64-lane bitonic sort on packed u64 keys (verified in prior kernel).
__device__ __forceinline__ unsigned long long bitonic64(unsigned long long key, int lane) {
    #pragma unroll
    for (int k = 2; k <= 64; k <<= 1) {
        #pragma unroll
        for (int jj = k >> 1; jj >= 1; jj >>= 1) {
            unsigned long long ok = __shfl_xor(key, jj, 64);
            bool keepMin = ((lane & k) == 0) == ((lane & jj) == 0);
            unsigned long long mn = (ok < key) ? ok : key;
            unsigned long long mx = (ok < key) ? key : ok;
            key = keepMin ? mn : mx;
        }
    }
    return key;
}

// ---------------------------------------------------------------------------
// K1: per-row top-12 smallest squared 2D distance. One block (256 thr) per row.
// Threshold-select structure (verified round-5/round-1-of-this-session):
//   T = 12th-smallest of the 256 per-thread minima is a provable upper bound
//   on the true 12th-smallest of the row. Filter the 16 register-resident
//   values per thread against T, prefix-compact survivors (expected ~12-14,
//   cap 64) into LDS, one final 64-lane bitonic sort, write.
//   Key = (f32 bits of s)<<32 | j — u64 order == (s, j) lexicographic.
//   Fallback (>64 survivors, pathological ties only): verified wave-local
//   12-pop path on the untouched s[]/bk registers.
// NOTE (round-3 post-mortem): do NOT fuse the MLP into this kernel. Per-row
// fusion breaks the MLP's scalar-weight addressing (12 pairs can't feed a
// wave; per-lane weight loads thrash L1) — measured 459us vs ~85us split.
// ---------------------------------------------------------------------------
__global__ __launch_bounds__(256, 6) void topk_rows(const float* __restrict__ x,
                                                    float* __restrict__ out) {
    const int i    = blockIdx.x;   // row
    const int t    = threadIdx.x;  // 0..255
    const int lane = t & 63;
    const int w    = t >> 6;       // wave 0..3
    const float4* x4 = (const float4*)x + (size_t)i * NN;

    // Stage: j = k*256 + t  (coalesced float4 loads)
    float s[16];
    #pragma unroll
    for (int k = 0; k < 16; ++k) {
        float4 v = x4[(k << 8) + t];
        s[k] = v.x * v.x + v.y * v.y;
    }

    // Per-thread min as packed key (ascending j scan, strict < => lowest j on tie)
    float bs = s[0]; int bj = t;
    #pragma unroll
    for (int k = 1; k < 16; ++k) {
        int j = (k << 8) + t;
        if (s[k] < bs) { bs = s[k]; bj = j; }
    }
    unsigned long long bk =
        ((unsigned long long)__float_as_uint(bs) << 32) | (unsigned)bj;

    __shared__ unsigned long long cand[64];        // survivor keys (cap 64)
    __shared__ unsigned long long wtop[4 * TOPK];  // per-wave top-12 minima
    __shared__ float Tsh;                          // threshold
    __shared__ int   cnt[4];                       // per-wave survivor counts

    // Phase A: each wave sorts its 64 lane-minima once; keep its top-12.
    {
        unsigned long long key = bitonic64(bk, lane);
        if (lane < TOPK) wtop[w * TOPK + lane] = key;
    }
    __syncthreads();

    // Phase B: wave 0 sorts the 48 candidates -> exact 12th-smallest minimum T.
    if (w == 0) {
        unsigned long long k2 = (lane < 4 * TOPK) ? wtop[lane] : ~0ULL;
        k2 = bitonic64(k2, lane);
        if (lane == TOPK - 1) Tsh = __uint_as_float((unsigned)(k2 >> 32));
    }
    __syncthreads();
    const float T = Tsh;

    // Phase C: filter register-resident values against T, count + prefix.
    int c = 0;
    #pragma unroll
    for (int k = 0; k < 16; ++k) c += (s[k] <= T) ? 1 : 0;

    int pfx = c;                                   // inclusive scan over wave
    #pragma unroll
    for (int off = 1; off < 64; off <<= 1) {
        int o = __shfl_up(pfx, off, 64);
        if (lane >= off) pfx += o;
    }
    if (lane == 63) cnt[w] = pfx;
    __syncthreads();

    const int total = cnt[0] + cnt[1] + cnt[2] + cnt[3];   // block-uniform

    if (total <= 64) {
        int base = 0;
        for (int ww = 0; ww < w; ++ww) base += cnt[ww];
        int o = base + (pfx - c);                  // exclusive offset
        #pragma unroll
        for (int k = 0; k < 16; ++k) {
            if (s[k] <= T)
                cand[o++] = ((unsigned long long)__float_as_uint(s[k]) << 32)
                            | (unsigned)((k << 8) + t);
        }
        __syncthreads();

        if (w == 0) {
            unsigned long long k3 = (lane < total) ? cand[lane] : ~0ULL;
            k3 = bitonic64(k3, lane);              // total >= 12 guaranteed
            if (lane < TOPK) {
                int   j  = (int)(k3 & 0xffffffffULL);
                float ss = __uint_as_float((unsigned)(k3 >> 32));
                float d  = sqrtf(ss + 2.0e-4f);    // sqrt(sum(x[:2]^2 + 1e-4))
                float m  = (d <= 1.0f) ? 1.0f : 0.0f;
                int p = i * TOPK + lane;
                out[OFF_MASK + p]        = m;
                out[OFF_IDX + 2 * p]     = (float)i;
                out[OFF_IDX + 2 * p + 1] = (float)j;
            }
        }
        return;                                    // uniform exit
    }

    // -----------------------------------------------------------------------
    // Fallback (pathological ties only): original wave-local 12-pop + merge.
    // s[] and bk are untouched by the filter phase.
    // -----------------------------------------------------------------------
    unsigned long long mykey = ~0ULL;
    for (int it = 0; it < TOPK; ++it) {
        unsigned long long vk = bk;
        #pragma unroll
        for (int off = 1; off < 64; off <<= 1) {
            unsigned long long ok = __shfl_xor(vk, off, 64);
            vk = (ok < vk) ? ok : vk;
        }
        if (lane == it) mykey = vk;                // record pop #it
        int wj = (int)(vk & 0xffffffffULL);        // winning j (this wave's range)
        if ((wj & 63) == lane) {                   // I own it: pop + recompute
            int kk = wj >> 8;
            #pragma unroll
            for (int k = 0; k < 16; ++k)
                if (k == kk) s[k] = 3.0e38f;
            float nbs = s[0]; int nbj = t;
            #pragma unroll
            for (int k = 1; k < 16; ++k) {
                int j = (k << 8) + t;
                if (s[k] < nbs) { nbs = s[k]; nbj = j; }
            }
            bk = ((unsigned long long)__float_as_uint(nbs) << 32) | (unsigned)nbj;
        }
    }
    if (lane < TOPK) cand[w * TOPK + lane] = mykey;
    __syncthreads();

    if (w == 0) {
        unsigned long long k3 = (lane < 4 * TOPK) ? cand[lane] : ~0ULL;
        k3 = bitonic64(k3, lane);
        if (lane < TOPK) {
            int   j  = (int)(k3 & 0xffffffffULL);
            float ss = __uint_as_float((unsigned)(k3 >> 32));
            float d  = sqrtf(ss + 2.0e-4f);
            float m  = (d <= 1.0f) ? 1.0f : 0.0f;
            int p = i * TOPK + lane;
            out[OFF_MASK + p]        = m;
            out[OFF_IDX + 2 * p]     = (float)i;
            out[OFF_IDX + 2 * p + 1] = (float)j;
        }
    }
}

// ---------------------------------------------------------------------------
// K2: per-neighbor MLP 6->64->128->64->1.
// Block = 512 threads = 8 waves handling 64 pairs: lane (t&63) = pair,
// wave chunk ch = readfirstlane(t>>6) -> SGPR, so ALL weight/bias addresses
// are compiler-provably scalar => s_load + v_fmac_f32(v,s,v), zero VMEM in
// the inner loops. Activations pass via LDS [neuron][pair] (lane=pair ->
// conflict-free). 50 KB LDS -> 3 blocks/CU, 24 waves/CU.
// ---------------------------------------------------------------------------
__global__ __launch_bounds__(512, 6) void mlp_block(
        const float* __restrict__ x, const float* __restrict__ rp,
        const float* __restrict__ W1, const float* __restrict__ b1,
        const float* __restrict__ W2, const float* __restrict__ b2,
        const float* __restrict__ W3, const float* __restrict__ b3,
        const float* __restrict__ W4, const float* __restrict__ b4,
        float* out) {
    __shared__ float h1s[64 * 64];    // [m][pair] 16 KB
    __shared__ float h2s[128 * 64];   // [j][pair] 32 KB
    __shared__ float p4s[8 * 64];     // [chunk][pair] 2 KB

    const int t  = threadIdx.x;
    const int pl = t & 63;                                   // pair lane (vector)
    const int ch = __builtin_amdgcn_readfirstlane(t >> 6);   // chunk (SGPR!)
    const int p  = blockIdx.x * 64 + pl;
    const int i  = p / TOPK;
    const int j  = (int)out[OFF_IDX + 2 * p + 1];   // written by topk_rows

    const float4 v = ((const float4*)x)[(size_t)i * NN + j];
    const float d  = sqrtf(v.x * v.x + v.y * v.y + 2.0e-4f);
    float xin[6];
    xin[0] = v.x; xin[1] = v.y; xin[2] = v.z; xin[3] = v.w;
    xin[4] = (i == j) ? 1.0f : 0.0f;
    xin[5] = d - rp[0];

    // Phase 1: h1 neurons [ch*8, ch*8+8)   (weights via s_load)
    #pragma unroll
    for (int q = 0; q < 8; ++q) {
        int m = ch * 8 + q;
        const float* w = W1 + m * 6;
        float a = b1[m];
        #pragma unroll
        for (int c = 0; c < 6; ++c) a += w[c] * xin[c];
        h1s[m * 64 + pl] = fmaxf(a, 0.0f);
    }
    __syncthreads();

    // Phase 2: h2 neurons [ch*16, ch*16+16), k streamed in parts of 16
    float acc[16];
    #pragma unroll
    for (int q = 0; q < 16; ++q) acc[q] = b2[ch * 16 + q];
    for (int part = 0; part < 4; ++part) {
        float h1r[16];
        #pragma unroll
        for (int k = 0; k < 16; ++k) h1r[k] = h1s[(part * 16 + k) * 64 + pl];
        #pragma unroll
        for (int q = 0; q < 16; ++q) {
            const float* w = W2 + (ch * 16 + q) * 64 + part * 16;  // scalar addr
            #pragma unroll
            for (int k = 0; k < 16; ++k) acc[q] += w[k] * h1r[k];
        }
    }
    #pragma unroll
    for (int q = 0; q < 16; ++q) h2s[(ch * 16 + q) * 64 + pl] = fmaxf(acc[q], 0.0f);
    __syncthreads();

    // Phase 3: h3 neurons [ch*8, ch*8+8), j streamed in parts of 16
    float h3[8];
    #pragma unroll
    for (int q = 0; q < 8; ++q) h3[q] = b3[ch * 8 + q];
    for (int part = 0; part < 8; ++part) {
        float h2r[16];
        #pragma unroll
        for (int k = 0; k < 16; ++k) h2r[k] = h2s[(part * 16 + k) * 64 + pl];
        #pragma unroll
        for (int q = 0; q < 8; ++q) {
            const float* w = W3 + (ch * 8 + q) * 128 + part * 16;  // scalar addr
            #pragma unroll
            for (int k = 0; k < 16; ++k) h3[q] += w[k] * h2r[k];
        }
    }
    // Layer 4 partial over my 8 h3 outputs
    float partial = 0.0f;
    #pragma unroll
    for (int q = 0; q < 8; ++q) partial += W4[ch * 8 + q] * fmaxf(h3[q], 0.0f);
    p4s[ch * 64 + pl] = partial;
    __syncthreads();

    // Phase 4: reduce the 8 chunk-partials per pair, apply bias + mask
    if (t < 64) {
        float s = b4[0];
        #pragma unroll
        for (int c = 0; c < 8; ++c) s += p4s[c * 64 + t];
        int pp = blockIdx.x * 64 + t;
        out[pp] = s * out[OFF_MASK + pp];
    }
}

// ---------------------------------------------------------------------------
extern "C" void kernel_launch(void* const* d_in, const int* in_sizes, int n_in,
                              void* d_out, int out_size, void* d_ws, size_t ws_size,
                              hipStream_t stream) {
    const float* x  = (const float*)d_in[0];
    const float* rp = (const float*)d_in[1];
    const float* W1 = (const float*)d_in[2];
    const float* b1 = (const float*)d_in[3];
    const float* W2 = (const float*)d_in[4];
    const float* b2 = (const float*)d_in[5];
    const float* W3 = (const float*)d_in[6];
    const float* b3 = (const float*)d_in[7];
    const float* W4 = (const float*)d_in[8];
    const float* b4 = (const float*)d_in[9];
    float* out = (float*)d_out;

    topk_rows<<<NN, 256, 0, stream>>>(x, out);
    mlp_block<<<NP / 64, 512, 0, stream>>>(x, rp, W1, b1, W2, b2, W3, b3, W4, b4, out);
}